// Round 8
// baseline (1550.161 us; speedup 1.0000x reference)
//
#include <hip/hip_runtime.h>
#include <hip/hip_fp16.h>
#include <hip/hip_cooperative_groups.h>
#include <cmath>

namespace cg = cooperative_groups;

#define LNUM 6
#define DM   1152
#define DHEAD 256
#define NH   4
#define FF   6912
#define VOC  65536
#define HIST 4095
#define SEQ  4096
#define EPSV 1e-6f
#define NB   256
#define BS   512

// ---- ws float offsets (shared by coop + fallback) ----
#define QKV_O 0            // [6][1536]   zeroed
#define AP_O  9216         // [6][1152]   zeroed
#define DP_O  16128        // [6][1152]   zeroed
#define GU_O  23040        // [6][13824]  zeroed
#define LG_O  105984       // [65536]     zeroed
#define AMX_O 171520       // u64 packed argmax, zeroed
#define ZEND  171522
#define POP_O 171528       // [128][1024]
#define SPS_O 302600       // [128][4]
#define HIN_O 303112       // [6][1152]
#define HM_O  310024       // [6][1152]
#define AMV_O 316936       // [256] (fallback)
#define AMI_O 317192       // [256] (fallback)

struct P {
    const int* ids; const int* aflag;
    const float* kc; const float* vc;
    const int* tbl; const float* esc; const float* ezp;
    const float* w_in; const float* w_qn; const float* w_kn;
    const float* Wq; const float* Wk; const float* Wv; const float* Wo;
    const float* w_pa; const float* w_pf; const float* w_pof;
    const float* Wg; const float* Wu; const float* Wd;
    const float* w_fin; const float* Wlm;
    float* keys; float* vals; float* tok; float* ws;
};

__device__ __forceinline__ float bsum512(float v, float* red8) {
#pragma unroll
    for (int off = 32; off; off >>= 1) v += __shfl_xor(v, off);
    if ((threadIdx.x & 63) == 0) red8[threadIdx.x >> 6] = v;
    __syncthreads();
    float r = red8[0] + red8[1] + red8[2] + red8[3] +
              red8[4] + red8[5] + red8[6] + red8[7];
    __syncthreads();
    return r;
}

// copy history of layer l; part in [0,128)
__device__ __forceinline__ void copy_layer(const P& p, int l, int part) {
    int t = threadIdx.x;
#pragma unroll
    for (int rr = 0; rr < 2; ++rr) {            // 2 key rows/part
        int row = part * 2 + rr;
        const float* src = p.kc + ((size_t)l * 256 + row) * HIST;
        float* dst = p.keys + ((size_t)l * 256 + row) * SEQ;
        for (int s = t; s < HIST; s += BS) dst[s] = src[s];
    }
    const float4* vc4 = (const float4*)p.vc;
    float4* va4 = (float4*)p.vals;
#pragma unroll
    for (int rr = 0; rr < 4; ++rr) {            // 32 val rows/part
        int s = part * 32 + rr * 8 + (t >> 6);
        if (s < HIST)
            va4[((size_t)l * SEQ + s) * 64 + (t & 63)] =
                vc4[((size_t)l * HIST + s) * 64 + (t & 63)];
    }
}

// ==================== cooperative mega: 256 blocks x 512 threads ====================
__global__ __launch_bounds__(BS) void mega(P p) {
    cg::grid_group gg = cg::this_grid();
    __shared__ float sm[5632];
    const int t = threadIdx.x, bid = blockIdx.x;
    float* ws = p.ws;

    // ---------- P0: zero + embed + copy layer 0 ----------
    {
        for (int g = bid * BS + t; g < ZEND; g += NB * BS) ws[g] = 0.f;
        if (bid == 0) {
            int tk = p.ids[0];
            float sc = p.esc[tk], z = p.ezp[tk];
            const int* row = p.tbl + (size_t)tk * DM;
            for (int i = t; i < DM; i += BS) ws[HIN_O + i] = (float)row[i] * sc + z;
        }
        if (bid < 128) copy_layer(p, 0, bid);
    }
    gg.sync();

    for (int l = 0; l < LNUM; ++l) {
        float* QKV = ws + QKV_O + l * 1536;
        float* AP  = ws + AP_O + l * DM;
        float* DP  = ws + DP_O + l * DM;
        float* GU  = ws + GU_O + l * 13824;
        float* HIN = ws + HIN_O + l * DM;
        float* HM  = ws + HM_O + l * DM;
        float* POP = ws + POP_O;
        float* SPS = ws + SPS_O;
        float* keys_l = p.keys + (size_t)l * DHEAD * SEQ;
        float* vals_l = p.vals + (size_t)l * SEQ * DHEAD;

        // ---------- qkv phase ----------
        {
            float* xv = sm; float* red8 = sm + 1152;
            float4* qred = (float4*)(sm + 1216);
            if (l == 0) {
                for (int i = t; i < DM; i += BS) xv[i] = ws[HIN_O + i];
            } else {
                const float* hprev = ws + HM_O + (l - 1) * DM;
                const float* dprev = ws + DP_O + (l - 1) * DM;
                const float* wpof = p.w_pof + (l - 1) * DM;
                float ssd = 0.f;
                for (int i = t; i < DM; i += BS) { float d = dprev[i]; ssd += d * d; }
                ssd = bsum512(ssd, red8);
                float inv = 1.f / sqrtf(ssd / DM + EPSV);
                for (int i = t; i < DM; i += BS)
                    xv[i] = hprev[i] + wpof[i] * dprev[i] * inv;
            }
            __syncthreads();
            if (bid == 0) for (int i = t; i < DM; i += BS) HIN[i] = xv[i];
            float ss2 = 0.f;
            for (int i = t; i < DM; i += BS) { float v = xv[i]; ss2 += v * v; }
            ss2 = bsum512(ss2, red8);
            float inv2 = 1.f / sqrtf(ss2 / DM + EPSV);
            const float* w_in = p.w_in + l * DM;
            for (int i = t; i < DM; i += BS) xv[i] = w_in[i] * xv[i] * inv2;
            __syncthreads();
            if (bid < 96) {
                int cg = bid % 6, kc = bid / 6;     // 6 col-groups x 16 k-chunks(72)
                int f4c = t & 63, ks = t >> 6;      // 8 slices x 9 rows
                int jf = cg * 64 + f4c;
                const float4* W4; int jj4, nc4;
                if (jf < 256)      { W4 = (const float4*)(p.Wq + (size_t)l * DM * 1024); jj4 = jf;       nc4 = 256; }
                else if (jf < 320) { W4 = (const float4*)(p.Wk + (size_t)l * DM * 256);  jj4 = jf - 256; nc4 = 64; }
                else               { W4 = (const float4*)(p.Wv + (size_t)l * DM * 256);  jj4 = jf - 320; nc4 = 64; }
                int i0 = kc * 72 + ks * 9;
                float4 w[9];
#pragma unroll
                for (int r = 0; r < 9; ++r) w[r] = W4[(size_t)(i0 + r) * nc4 + jj4];
                float4 acc = {0, 0, 0, 0};
#pragma unroll
                for (int r = 0; r < 9; ++r) {
                    float xs = xv[i0 + r];
                    acc.x += xs * w[r].x; acc.y += xs * w[r].y;
                    acc.z += xs * w[r].z; acc.w += xs * w[r].w;
                }
                qred[t] = acc;
                __syncthreads();
                if (ks == 0) {
                    float sx = 0, sy = 0, sz = 0, sw = 0;
#pragma unroll
                    for (int k2 = 0; k2 < 8; ++k2) {
                        float4 r = qred[k2 * 64 + f4c];
                        sx += r.x; sy += r.y; sz += r.z; sw += r.w;
                    }
                    atomicAdd(&QKV[4 * jf + 0], sx); atomicAdd(&QKV[4 * jf + 1], sy);
                    atomicAdd(&QKV[4 * jf + 2], sz); atomicAdd(&QKV[4 * jf + 3], sw);
                }
            }
        }
        gg.sync();

        // ---------- attn phase (blocks 0..127) + next-layer copy (128..255) ----------
        if (bid < 128) {
            float* lq = sm;            // 1024
            float* lqf = sm + 1024;    // 1024
            float* lkn = sm + 2048;    // 256
            float* lkf = sm + 2304;    // 256
            float* lv  = sm + 2560;    // 256
            float* lp  = sm + 2816;    // 128
            float* red8 = sm + 2944;   // 8
            float* scr = sm + 3072;    // 2048
            int s0 = bid * 32;
            bool lastb = (bid == 127);
            float base = ((l % 6) != 5) ? 1000000.f : 10000.f;
            float c = 0.f, s = 0.f;
            if (t < 256) {
                int jm = t & 127;
                float theta = powf(base, -(float)(2 * jm) / 256.f);
                float ang = 4095.f * theta;
                c = __half2float(__float2half(cosf(ang)));
                s = __half2float(__float2half(sinf(ang)));
                for (int h = 0; h < NH; ++h) lq[h * 256 + t] = QKV[h * 256 + t];
                lkn[t] = QKV[1024 + t];
                lv[t]  = QKV[1280 + t];
            }
            __syncthreads();
            const float* wqn = p.w_qn + l * DHEAD;
            const float* wkn = p.w_kn + l * DHEAD;
            for (int h = 0; h < NH; ++h) {
                float v = (t < 256) ? lq[h * 256 + t] : 0.f;
                float ss = bsum512(v * v, red8);
                float qn = 0.f;
                if (t < 256) {
                    qn = wqn[t] * v / sqrtf(ss / 256.f + EPSV);
                    lq[h * 256 + t] = qn;
                }
                __syncthreads();
                if (t < 256) {
                    float partner = (t < 128) ? -lq[h * 256 + t + 128] : lq[h * 256 + t - 128];
                    lqf[h * 256 + t] = qn * c + partner * s;
                }
                __syncthreads();
            }
            {
                float v = (t < 256) ? lkn[t] : 0.f;
                float ss = bsum512(v * v, red8);
                float kn = 0.f;
                if (t < 256) { kn = wkn[t] * v / sqrtf(ss / 256.f + EPSV); lkn[t] = kn; }
                __syncthreads();
                if (t < 256) {
                    float pr = (t < 128) ? -lkn[t + 128] : lkn[t - 128];
                    lkf[t] = kn * c + pr * s;
                }
                __syncthreads();
            }
            if (lastb && t < 256) {
                keys_l[(size_t)t * SEQ + (SEQ - 1)] = lkf[t];
                vals_l[(size_t)(SEQ - 1) * DHEAD + t] = lv[t];
            }
            int sl = t & 31, dc = t >> 5;      // 16 d-chunks of 16
            int sg = s0 + sl;
            bool self = lastb && (sl == 31);
            float a0 = 0, a1 = 0, a2 = 0, a3 = 0;
#pragma unroll
            for (int dd = 0; dd < 16; ++dd) {
                int d = dc * 16 + dd;
                float kv = self ? lkf[d] : keys_l[(size_t)d * SEQ + sg];
                a0 += lqf[d] * kv; a1 += lqf[256 + d] * kv;
                a2 += lqf[512 + d] * kv; a3 += lqf[768 + d] * kv;
            }
            scr[dc * 128 + sl]      = a0;
            scr[dc * 128 + 32 + sl] = a1;
            scr[dc * 128 + 64 + sl] = a2;
            scr[dc * 128 + 96 + sl] = a3;
            __syncthreads();
            if (t < 128) {
                int hh = t >> 5, si = t & 31;
                int af = p.aflag[0];
                float mk = (s0 + si > 0) ? -128.f * (float)af : 0.f;
                float sc_ = 0.f;
#pragma unroll
                for (int d16 = 0; d16 < 16; ++d16) sc_ += scr[d16 * 128 + hh * 32 + si];
                lp[hh * 32 + si] = expf(sc_ + mk);
            }
            __syncthreads();
            if (t < NH) {
                float su = 0.f;
                for (int i = 0; i < 32; ++i) su += lp[t * 32 + i];
                SPS[bid * NH + t] = su;
            }
            int f4 = t & 63, hp = (t >> 6) & 3, sr = t >> 8;  // 2 s-groups of 16
            const float4* V4 = (const float4*)vals_l;
            float4 acc = {0, 0, 0, 0};
#pragma unroll
            for (int ss_ = 0; ss_ < 16; ++ss_) {
                int sI = sr * 16 + ss_;
                float4 vv = (lastb && sI == 31) ? ((float4*)lv)[f4]
                                                : V4[(size_t)(s0 + sI) * 64 + f4];
                float pp = lp[hp * 32 + sI];
                acc.x += pp * vv.x; acc.y += pp * vv.y;
                acc.z += pp * vv.z; acc.w += pp * vv.w;
            }
            ((float4*)scr)[sr * 256 + hp * 64 + f4] = acc;
            __syncthreads();
            POP[(size_t)bid * 1024 + t]       = scr[t] + scr[1024 + t];
            POP[(size_t)bid * 1024 + 512 + t] = scr[512 + t] + scr[1536 + t];
        } else if (l + 1 < LNUM) {
            copy_layer(p, l + 1, bid - 128);
        }
        gg.sync();

        // ---------- wo phase (80 units) ----------
        if (bid < 80) {
            float* hinv = sm;          // 4
            float* xl = sm + 8;        // 64
            float* red8 = sm + 72;     // 8
            float* wored = sm + 80;    // 512
            int cgp = bid % 5, kc = bid / 5;
            for (int h = 0; h < NH; ++h) {
                float v = (t < 128) ? SPS[t * NH + h] : 0.f;
                float tot = bsum512(v, red8);
                if (t == 0) hinv[h] = 1.f / tot;
            }
            __syncthreads();
            int i0 = kc * 64;
            if (t < 64) {
                float a = 0.f;
#pragma unroll 8
                for (int b = 0; b < 128; ++b) a += POP[(size_t)b * 1024 + i0 + t];
                xl[t] = a * hinv[(i0 + t) >> 8];
            }
            __syncthreads();
            const float* Wo_l = p.Wo + (size_t)l * 1024 * DM;
            int j = cgp * 256 + (t & 255);
            int kr = t >> 8;                 // 2 row-halves of 32
            float acc = 0.f;
            if (j < DM) {
#pragma unroll
                for (int r = 0; r < 32; ++r) {
                    int li = kr * 32 + r;
                    acc += xl[li] * Wo_l[(size_t)(i0 + li) * DM + j];
                }
            }
            wored[t] = acc;
            __syncthreads();
            if (t < 256 && j < DM) atomicAdd(&AP[j], wored[t] + wored[t + 256]);
        }
        gg.sync();

        // ---------- gu phase (486 units) ----------
        {
            float* xv = sm; float* red8 = sm + 1152;
            float4* gred = (float4*)(sm + 1216);
            float ssa = 0.f;
            for (int i = t; i < DM; i += BS) { float a = AP[i]; ssa += a * a; }
            ssa = bsum512(ssa, red8);
            float inv = 1.f / sqrtf(ssa / DM + EPSV);
            const float* wpa = p.w_pa + l * DM;
            for (int i = t; i < DM; i += BS) xv[i] = HIN[i] + wpa[i] * AP[i] * inv;
            __syncthreads();
            if (bid == 0) for (int i = t; i < DM; i += BS) HM[i] = xv[i];
            float ssb = 0.f;
            for (int i = t; i < DM; i += BS) { float v = xv[i]; ssb += v * v; }
            ssb = bsum512(ssb, red8);
            float inv2 = 1.f / sqrtf(ssb / DM + EPSV);
            const float* wpf = p.w_pf + l * DM;
            for (int i = t; i < DM; i += BS) xv[i] = wpf[i] * xv[i] * inv2;
            __syncthreads();
            int f4c = t & 63, ks = t >> 6;       // 8 slices x 16 rows
            for (int u = bid; u < 486; u += NB) {
                int cgi = u % 54, kc = u / 54;
                bool isU = cgi >= 27;
                int cg = isU ? cgi - 27 : cgi;
                const float4* W4 = (const float4*)((isU ? p.Wu : p.Wg) + (size_t)l * DM * FF);
                int colf = cg * 64 + f4c;
                int i0 = kc * 128 + ks * 16;
                float4 w[16];
#pragma unroll
                for (int r = 0; r < 16; ++r) w[r] = W4[(size_t)(i0 + r) * 1728 + colf];
                float4 acc = {0, 0, 0, 0};
#pragma unroll
                for (int r = 0; r < 16; ++r) {
                    float xs = xv[i0 + r];
                    acc.x += xs * w[r].x; acc.y += xs * w[r].y;
                    acc.z += xs * w[r].z; acc.w += xs * w[r].w;
                }
                gred[t] = acc;
                __syncthreads();
                if (ks == 0) {
                    float sx = 0, sy = 0, sz = 0, sw = 0;
#pragma unroll
                    for (int k2 = 0; k2 < 8; ++k2) {
                        float4 r = gred[k2 * 64 + f4c];
                        sx += r.x; sy += r.y; sz += r.z; sw += r.w;
                    }
                    float* dst = GU + (isU ? FF : 0) + 4 * colf;
                    atomicAdd(dst + 0, sx); atomicAdd(dst + 1, sy);
                    atomicAdd(dst + 2, sz); atomicAdd(dst + 3, sw);
                }
                __syncthreads();
            }
        }
        gg.sync();

        // ---------- wd phase (486 units) ----------
        {
            float* m = sm;                        // 128
            float4* wred = (float4*)(sm + 128);   // 512 f4
            const float4* Wd4 = (const float4*)(p.Wd + (size_t)l * FF * DM);
            int f4c = t & 31, ks = t >> 5;        // 16 slices x 8 rows
            for (int u = bid; u < 486; u += NB) {
                int cg = u % 9, kc = u / 9;
                int i0 = kc * 128;
                __syncthreads();
                if (t < 128) {
                    float g = GU[i0 + t], uu = GU[FF + i0 + t];
                    float gl = 0.5f * g * (1.f + tanhf(0.7978845608028654f * (g + 0.044715f * g * g * g)));
                    m[t] = gl * uu;
                }
                __syncthreads();
                int col4 = cg * 32 + f4c;
                float4 w[8];
#pragma unroll
                for (int r = 0; r < 8; ++r) w[r] = Wd4[(size_t)(i0 + ks * 8 + r) * 288 + col4];
                float4 acc = {0, 0, 0, 0};
#pragma unroll
                for (int r = 0; r < 8; ++r) {
                    float xs = m[ks * 8 + r];
                    acc.x += xs * w[r].x; acc.y += xs * w[r].y;
                    acc.z += xs * w[r].z; acc.w += xs * w[r].w;
                }
                wred[t] = acc;
                __syncthreads();
                if (t < 32) {
                    float sx = 0, sy = 0, sz = 0, sw = 0;
#pragma unroll
                    for (int k2 = 0; k2 < 16; ++k2) {
                        float4 r = wred[k2 * 32 + t];
                        sx += r.x; sy += r.y; sz += r.z; sw += r.w;
                    }
                    int col4b = cg * 32 + t;
                    atomicAdd(&DP[4 * col4b + 0], sx); atomicAdd(&DP[4 * col4b + 1], sy);
                    atomicAdd(&DP[4 * col4b + 2], sz); atomicAdd(&DP[4 * col4b + 3], sw);
                }
            }
        }
        gg.sync();
    }

    // ---------- logits phase (2048 units, 8 rounds/block) ----------
    {
        float* xv = sm; float* red8 = sm + 1152;
        float4* lred = (float4*)(sm + 1216);
        const float* DP5 = ws + DP_O + 5 * DM;
        const float* HM5 = ws + HM_O + 5 * DM;
        const float* wpof5 = p.w_pof + 5 * DM;
        float ss = 0.f;
        for (int i = t; i < DM; i += BS) { float d = DP5[i]; ss += d * d; }
        ss = bsum512(ss, red8);
        float inv = 1.f / sqrtf(ss / DM + EPSV);
        for (int i = t; i < DM; i += BS) xv[i] = HM5[i] + wpof5[i] * DP5[i] * inv;
        __syncthreads();
        float s2 = 0.f;
        for (int i = t; i < DM; i += BS) { float v = xv[i]; s2 += v * v; }
        s2 = bsum512(s2, red8);
        float inv2 = 1.f / sqrtf(s2 / DM + EPSV);
        for (int i = t; i < DM; i += BS) xv[i] = p.w_fin[i] * xv[i] * inv2;
        __syncthreads();
        const float4* W4 = (const float4*)p.Wlm;
        float* LG = ws + LG_O;
        int f4c = t & 63, ks = t >> 6;           // 8 slices x 18 rows
        for (int u = bid; u < 2048; u += NB) {
            int cg = u & 255, kc = u >> 8;
            int colf = cg * 64 + f4c;
            int i0 = kc * 144 + ks * 18;
            float4 w[18];
#pragma unroll
            for (int r = 0; r < 18; ++r) w[r] = W4[(size_t)(i0 + r) * 16384 + colf];
            float4 acc = {0, 0, 0, 0};
#pragma unroll
            for (int r = 0; r < 18; ++r) {
                float xs = xv[i0 + r];
                acc.x += xs * w[r].x; acc.y += xs * w[r].y;
                acc.z += xs * w[r].z; acc.w += xs * w[r].w;
            }
            lred[t] = acc;
            __syncthreads();
            if (ks == 0) {
                float sx = 0, sy = 0, sz = 0, sw = 0;
#pragma unroll
                for (int k2 = 0; k2 < 8; ++k2) {
                    float4 r = lred[k2 * 64 + f4c];
                    sx += r.x; sy += r.y; sz += r.z; sw += r.w;
                }
                atomicAdd(&LG[4 * colf + 0], sx); atomicAdd(&LG[4 * colf + 1], sy);
                atomicAdd(&LG[4 * colf + 2], sz); atomicAdd(&LG[4 * colf + 3], sw);
            }
            __syncthreads();
        }
    }
    gg.sync();

    // ---------- argmax: packed u64 atomicMax ----------
    {
        unsigned long long* smu = (unsigned long long*)sm;
        unsigned long long pk = 0;
        if (t < 256) {
            int c = bid * 256 + t;
            float v = ws[LG_O + c];
            unsigned bits = __float_as_uint(v);
            unsigned key = (bits & 0x80000000u) ? ~bits : (bits | 0x80000000u);
            pk = ((unsigned long long)key << 32) | (unsigned)(~c);
        }
        if (t < 256) smu[t] = pk;
        __syncthreads();
        for (int off = 128; off; off >>= 1) {
            if (t < off) { if (smu[t + off] > smu[t]) smu[t] = smu[t + off]; }
            __syncthreads();
        }
        if (t == 0) atomicMax((unsigned long long*)(ws + AMX_O), smu[0]);
    }
    gg.sync();
    if (bid == 0 && t == 0) {
        unsigned long long pk = *(unsigned long long*)(ws + AMX_O);
        unsigned c = ~(unsigned)(pk & 0xFFFFFFFFull);
        p.tok[0] = (float)c;
    }
}

// ==================== fallback kernels (round-7 verbatim, known 579 µs) ====================
__device__ __forceinline__ float block_sum256(float v, float* red4) {
#pragma unroll
    for (int off = 32; off; off >>= 1) v += __shfl_xor(v, off);
    int t = threadIdx.x;
    if ((t & 63) == 0) red4[t >> 6] = v;
    __syncthreads();
    float r = red4[0] + red4[1] + red4[2] + red4[3];
    __syncthreads();
    return r;
}

__global__ __launch_bounds__(256) void gk_copy(const float* __restrict__ kc,
                                               const float* __restrict__ vc,
                                               float* __restrict__ keys,
                                               float* __restrict__ vals) {
    int b = blockIdx.x;
    if (b < 24576) {
        int row = b >> 4;
        int s = ((b & 15) << 8) + threadIdx.x;
        if (s < HIST) keys[(size_t)row * SEQ + s] = kc[(size_t)row * HIST + s];
    } else {
        int r = (b - 24576) * 4 + (threadIdx.x >> 6);
        int d4 = threadIdx.x & 63;
        if (r < LNUM * HIST) {
            int l = r / HIST, sI = r - l * HIST;
            ((float4*)(vals + ((size_t)l * SEQ + sI) * DHEAD))[d4] =
                ((const float4*)(vc + (size_t)r * DHEAD))[d4];
        }
    }
}

__global__ __launch_bounds__(256) void gk_qkv(
    const float* __restrict__ Wq, const float* __restrict__ Wk, const float* __restrict__ Wv,
    const float* __restrict__ w_in, const float* __restrict__ w_pof_prev,
    const float* __restrict__ hprev, const float* __restrict__ dprev,
    const int* __restrict__ ids, const int* __restrict__ tbl,
    const float* __restrict__ escale, const float* __restrict__ ezp,
    float* __restrict__ hin_out, float* __restrict__ qkv_out, int has_prev) {
    __shared__ float xv[DM];
    __shared__ float red4[4];
    __shared__ float4 qred[256];
    int t = threadIdx.x;
    if (has_prev) {
        float ss = 0.f;
        for (int i = t; i < DM; i += 256) { float d = dprev[i]; ss += d * d; }
        ss = block_sum256(ss, red4);
        float inv = 1.f / sqrtf(ss / DM + EPSV);
        for (int i = t; i < DM; i += 256)
            xv[i] = hprev[i] + w_pof_prev[i] * dprev[i] * inv;
    } else {
        int tok = ids[0];
        float sc = escale[tok], z = ezp[tok];
        const int* row = tbl + (size_t)tok * DM;
        for (int i = t; i < DM; i += 256) xv[i] = (float)row[i] * sc + z;
    }
    __syncthreads();
    if (blockIdx.x == 0 && blockIdx.y == 0)
        for (int i = t; i < DM; i += 256) hin_out[i] = xv[i];
    float ss = 0.f;
    for (int i = t; i < DM; i += 256) { float v = xv[i]; ss += v * v; }
    ss = block_sum256(ss, red4);
    float inv = 1.f / sqrtf(ss / DM + EPSV);
    for (int i = t; i < DM; i += 256) xv[i] = w_in[i] * xv[i] * inv;
    __syncthreads();
    int f4c = t & 63, ks = t >> 6;
    int jf = blockIdx.x * 64 + f4c;
    const float4* W4; int jj4, ncol4;
    if (jf < 256)      { W4 = (const float4*)Wq; jj4 = jf;       ncol4 = 256; }
    else if (jf < 320) { W4 = (const float4*)Wk; jj4 = jf - 256; ncol4 = 64; }
    else               { W4 = (const float4*)Wv; jj4 = jf - 320; ncol4 = 64; }
    int i0 = blockIdx.y * 64 + ks * 16;
    float4 w[16];
#pragma unroll
    for (int r = 0; r < 16; ++r) w[r] = W4[(size_t)(i0 + r) * ncol4 + jj4];
    float4 acc = {0, 0, 0, 0};
#pragma unroll
    for (int r = 0; r < 16; ++r) {
        float xs = xv[i0 + r];
        acc.x += xs * w[r].x; acc.y += xs * w[r].y;
        acc.z += xs * w[r].z; acc.w += xs * w[r].w;
    }
    qred[t] = acc;
    __syncthreads();
    if (ks == 0) {
        float4 a = qred[f4c], b = qred[64 + f4c], c = qred[128 + f4c], d = qred[192 + f4c];
        atomicAdd(&qkv_out[4 * jf + 0], a.x + b.x + c.x + d.x);
        atomicAdd(&qkv_out[4 * jf + 1], a.y + b.y + c.y + d.y);
        atomicAdd(&qkv_out[4 * jf + 2], a.z + b.z + c.z + d.z);
        atomicAdd(&qkv_out[4 * jf + 3], a.w + b.w + c.w + d.w);
    }
}

__global__ __launch_bounds__(256) void gk_attn(
    const float* __restrict__ qkv, const float* __restrict__ w_qn,
    const float* __restrict__ w_kn, const int* __restrict__ attn_flag,
    float* __restrict__ keys_l, float* __restrict__ vals_l,
    float* __restrict__ po_part, float* __restrict__ sum_part, float rope_base) {
    __shared__ float lq[NH * DHEAD];
    __shared__ float lqf[NH * DHEAD];
    __shared__ float lkn[DHEAD];
    __shared__ float lkf[DHEAD];
    __shared__ float lv[DHEAD];
    __shared__ float lp[NH * 32];
    __shared__ float red4[4];
    int t = threadIdx.x;
    int s0 = blockIdx.x * 32;
    bool last = (blockIdx.x == gridDim.x - 1);
    int jm = t & 127;
    float theta = powf(rope_base, -(float)(2 * jm) / 256.f);
    float ang = 4095.f * theta;
    float c = __half2float(__float2half(cosf(ang)));
    float s = __half2float(__float2half(sinf(ang)));
    for (int h = 0; h < NH; ++h) lq[h * 256 + t] = qkv[h * 256 + t];
    lkn[t] = qkv[1024 + t];
    lv[t]  = qkv[1280 + t];
    __syncthreads();
    for (int h = 0; h < NH; ++h) {
        float v = lq[h * 256 + t];
        float ss = block_sum256(v * v, red4);
        float inv = 1.f / sqrtf(ss / 256.f + EPSV);
        float qn = w_qn[t] * v * inv;
        lq[h * 256 + t] = qn;
        __syncthreads();
        float partner = (t < 128) ? -lq[h * 256 + t + 128] : lq[h * 256 + t - 128];
        lqf[h * 256 + t] = qn * c + partner * s;
    }
    {
        float v = lkn[t];
        float ss = block_sum256(v * v, red4);
        float inv = 1.f / sqrtf(ss / 256.f + EPSV);
        float kn = w_kn[t] * v * inv;
        lkn[t] = kn;
        __syncthreads();
        float partner = (t < 128) ? -lkn[t + 128] : lkn[t - 128];
        lkf[t] = kn * c + partner * s;
    }
    __syncthreads();
    if (last) {
        keys_l[(size_t)t * SEQ + (SEQ - 1)] = lkf[t];
        vals_l[(size_t)(SEQ - 1) * DHEAD + t] = lv[t];
    }
    int sl = t & 31, dc = t >> 5;
    int sg = s0 + sl;
    bool self = last && (sl == 31);
    float a0 = 0, a1 = 0, a2 = 0, a3 = 0;
#pragma unroll 4
    for (int dd = 0; dd < 32; ++dd) {
        int d = dc * 32 + dd;
        float kv = self ? lkf[d] : keys_l[(size_t)d * SEQ + sg];
        a0 += lqf[0 * 256 + d] * kv;
        a1 += lqf[1 * 256 + d] * kv;
        a2 += lqf[2 * 256 + d] * kv;
        a3 += lqf[3 * 256 + d] * kv;
    }
    __syncthreads();
    lq[0 * 256 + t] = a0; lq[1 * 256 + t] = a1; lq[2 * 256 + t] = a2; lq[3 * 256 + t] = a3;
    __syncthreads();
    if (t < 32) {
        int af = attn_flag[0];
        float mk = (s0 + t > 0) ? -128.f * (float)af : 0.f;
        for (int h = 0; h < NH; ++h) {
            float sc_ = 0.f;
#pragma unroll
            for (int d8 = 0; d8 < 8; ++d8) sc_ += lq[h * 256 + d8 * 32 + t];
            lp[h * 32 + t] = expf(sc_ + mk);
        }
    }
    __syncthreads();
    if (t < NH) {
        float su = 0.f;
        for (int i = 0; i < 32; ++i) su += lp[t * 32 + i];
        sum_part[blockIdx.x * NH + t] = su;
    }
    float p0 = 0, p1 = 0, p2 = 0, p3 = 0;
#pragma unroll 4
    for (int ss_ = 0; ss_ < 32; ++ss_) {
        float v = (last && ss_ == 31) ? lv[t] : vals_l[(size_t)(s0 + ss_) * DHEAD + t];
        p0 += lp[0 * 32 + ss_] * v;
        p1 += lp[1 * 32 + ss_] * v;
        p2 += lp[2 * 32 + ss_] * v;
        p3 += lp[3 * 32 + ss_] * v;
    }
    float* po = po_part + (size_t)blockIdx.x * NH * DHEAD;
    po[0 * 256 + t] = p0; po[1 * 256 + t] = p1; po[2 * 256 + t] = p2; po[3 * 256 + t] = p3;
}

__global__ __launch_bounds__(256) void gk_wo(
    const float* __restrict__ po_part, const float* __restrict__ sum_part,
    const float* __restrict__ Wo_l, float* __restrict__ aproj) {
    __shared__ float x[64];
    __shared__ float hinv[NH];
    __shared__ float red4[4];
    int t = threadIdx.x;
    for (int h = 0; h < NH; ++h) {
        float v = (t < 128) ? sum_part[t * NH + h] : 0.f;
        float tot = block_sum256(v, red4);
        if (t == 0) hinv[h] = 1.f / tot;
    }
    __syncthreads();
    int i0 = blockIdx.y * 64;
    if (t < 64) {
        float a = 0.f;
#pragma unroll 8
        for (int b = 0; b < 128; ++b) a += po_part[(size_t)b * 1024 + i0 + t];
        x[t] = a * hinv[(i0 + t) >> 8];
    }
    __syncthreads();
    int j = blockIdx.x * 256 + t;
    if (j < DM) {
        float acc = 0.f;
#pragma unroll 4
        for (int ii = 0; ii < 64; ++ii)
            acc += x[ii] * Wo_l[(size_t)(i0 + ii) * DM + j];
        atomicAdd(&aproj[j], acc);
    }
}

__global__ __launch_bounds__(256) void gk_gu(
    const float* __restrict__ Wg_l, const float* __restrict__ Wu_l,
    const float* __restrict__ w_pa, const float* __restrict__ w_pf,
    const float* __restrict__ hin, const float* __restrict__ aproj,
    float* __restrict__ hmid_out, float* __restrict__ gu_out) {
    __shared__ float xv[DM];
    __shared__ float red4[4];
    __shared__ float4 gred[256];
    int t = threadIdx.x;
    float ss = 0.f;
    for (int i = t; i < DM; i += 256) { float a = aproj[i]; ss += a * a; }
    ss = block_sum256(ss, red4);
    float inv = 1.f / sqrtf(ss / DM + EPSV);
    for (int i = t; i < DM; i += 256) xv[i] = hin[i] + w_pa[i] * aproj[i] * inv;
    __syncthreads();
    if (blockIdx.x == 0 && blockIdx.y == 0)
        for (int i = t; i < DM; i += 256) hmid_out[i] = xv[i];
    float s2 = 0.f;
    for (int i = t; i < DM; i += 256) { float v = xv[i]; s2 += v * v; }
    s2 = block_sum256(s2, red4);
    float inv2 = 1.f / sqrtf(s2 / DM + EPSV);
    for (int i = t; i < DM; i += 256) xv[i] = w_pf[i] * xv[i] * inv2;
    __syncthreads();
    int f4c = t & 63, ks = t >> 6;
    int cgi = blockIdx.x;
    bool isU = cgi >= 27;
    int cg = isU ? cgi - 27 : cgi;
    const float4* W4 = (const float4*)(isU ? Wu_l : Wg_l);
    int colf4 = cg * 64 + f4c;
    int i0 = blockIdx.y * 64 + ks * 16;
    float4 w[16];
#pragma unroll
    for (int r = 0; r < 16; ++r) w[r] = W4[(size_t)(i0 + r) * 1728 + colf4];
    float4 acc = {0, 0, 0, 0};
#pragma unroll
    for (int r = 0; r < 16; ++r) {
        float xs = xv[i0 + r];
        acc.x += xs * w[r].x; acc.y += xs * w[r].y;
        acc.z += xs * w[r].z; acc.w += xs * w[r].w;
    }
    gred[t] = acc;
    __syncthreads();
    if (ks == 0) {
        float4 a = gred[f4c], b = gred[64 + f4c], c = gred[128 + f4c], d = gred[192 + f4c];
        float* dst = gu_out + (isU ? FF : 0) + 4 * colf4;
        atomicAdd(dst + 0, a.x + b.x + c.x + d.x);
        atomicAdd(dst + 1, a.y + b.y + c.y + d.y);
        atomicAdd(dst + 2, a.z + b.z + c.z + d.z);
        atomicAdd(dst + 3, a.w + b.w + c.w + d.w);
    }
}

__global__ __launch_bounds__(256) void gk_wd(const float* __restrict__ gu,
                                             const float* __restrict__ Wd_l,
                                             float* __restrict__ dproj) {
    __shared__ float m[64];
    __shared__ float4 wred[256];
    int t = threadIdx.x;
    int i0 = blockIdx.y * 64;
    if (t < 64) {
        float g = gu[i0 + t], u = gu[FF + i0 + t];
        float gl = 0.5f * g * (1.f + tanhf(0.7978845608028654f * (g + 0.044715f * g * g * g)));
        m[t] = gl * u;
    }
    __syncthreads();
    int f4c = t & 63, ks = t >> 6;
    int col4 = blockIdx.x * 64 + f4c;
    float4 acc = {0, 0, 0, 0};
    if (col4 < 288) {
        const float4* W4 = (const float4*)Wd_l;
        float4 w[16];
#pragma unroll
        for (int r = 0; r < 16; ++r) w[r] = W4[(size_t)(i0 + ks * 16 + r) * 288 + col4];
#pragma unroll
        for (int r = 0; r < 16; ++r) {
            float xs = m[ks * 16 + r];
            acc.x += xs * w[r].x; acc.y += xs * w[r].y;
            acc.z += xs * w[r].z; acc.w += xs * w[r].w;
        }
    }
    wred[t] = acc;
    __syncthreads();
    if (ks == 0 && col4 < 288) {
        float4 a = wred[f4c], b = wred[64 + f4c], c = wred[128 + f4c], d = wred[192 + f4c];
        atomicAdd(&dproj[4 * col4 + 0], a.x + b.x + c.x + d.x);
        atomicAdd(&dproj[4 * col4 + 1], a.y + b.y + c.y + d.y);
        atomicAdd(&dproj[4 * col4 + 2], a.z + b.z + c.z + d.z);
        atomicAdd(&dproj[4 * col4 + 3], a.w + b.w + c.w + d.w);
    }
}

__global__ __launch_bounds__(256) void gk_logits(
    const float* __restrict__ W_lm, const float* __restrict__ w_pof5,
    const float* __restrict__ w_fin, const float* __restrict__ hmid5,
    const float* __restrict__ dproj5, float* __restrict__ lg) {
    __shared__ float xv[DM];
    __shared__ float red4[4];
    __shared__ float4 lred[256];
    int t = threadIdx.x;
    float ss = 0.f;
    for (int i = t; i < DM; i += 256) { float d = dproj5[i]; ss += d * d; }
    ss = block_sum256(ss, red4);
    float inv = 1.f / sqrtf(ss / DM + EPSV);
    for (int i = t; i < DM; i += 256) xv[i] = hmid5[i] + w_pof5[i] * dproj5[i] * inv;
    __syncthreads();
    float s2 = 0.f;
    for (int i = t; i < DM; i += 256) { float v = xv[i]; s2 += v * v; }
    s2 = block_sum256(s2, red4);
    float inv2 = 1.f / sqrtf(s2 / DM + EPSV);
    for (int i = t; i < DM; i += 256) xv[i] = w_fin[i] * xv[i] * inv2;
    __syncthreads();
    int f4c = t & 63, ks = t >> 6;
    int colf4 = blockIdx.x * 64 + f4c;
    int i0 = blockIdx.y * 64 + ks * 16;
    const float4* W4 = (const float4*)W_lm;
    float4 w[16];
#pragma unroll
    for (int r = 0; r < 16; ++r) w[r] = W4[(size_t)(i0 + r) * 16384 + colf4];
    float4 acc = {0, 0, 0, 0};
#pragma unroll
    for (int r = 0; r < 16; ++r) {
        float xs = xv[i0 + r];
        acc.x += xs * w[r].x; acc.y += xs * w[r].y;
        acc.z += xs * w[r].z; acc.w += xs * w[r].w;
    }
    lred[t] = acc;
    __syncthreads();
    if (ks == 0) {
        float4 a = lred[f4c], b = lred[64 + f4c], c = lred[128 + f4c], d = lred[192 + f4c];
        atomicAdd(&lg[4 * colf4 + 0], a.x + b.x + c.x + d.x);
        atomicAdd(&lg[4 * colf4 + 1], a.y + b.y + c.y + d.y);
        atomicAdd(&lg[4 * colf4 + 2], a.z + b.z + c.z + d.z);
        atomicAdd(&lg[4 * colf4 + 3], a.w + b.w + c.w + d.w);
    }
}

__global__ __launch_bounds__(256) void gk_amax1(const float* __restrict__ lg,
                                                float* __restrict__ pv, float* __restrict__ pi) {
    __shared__ float rv[256];
    __shared__ int ri[256];
    int t = threadIdx.x;
    int c = blockIdx.x * 256 + t;
    rv[t] = lg[c]; ri[t] = c;
    __syncthreads();
    for (int off = 128; off > 0; off >>= 1) {
        if (t < off) {
            float ov = rv[t + off]; int oi = ri[t + off];
            if (ov > rv[t] || (ov == rv[t] && oi < ri[t])) { rv[t] = ov; ri[t] = oi; }
        }
        __syncthreads();
    }
    if (t == 0) { pv[blockIdx.x] = rv[0]; pi[blockIdx.x] = (float)ri[0]; }
}

__global__ __launch_bounds__(256) void gk_amax2(const float* __restrict__ pv,
                                                const float* __restrict__ pi,
                                                float* __restrict__ tok_out) {
    __shared__ float rv[256];
    __shared__ int ri[256];
    int t = threadIdx.x;
    rv[t] = pv[t]; ri[t] = (int)pi[t];
    __syncthreads();
    for (int off = 128; off > 0; off >>= 1) {
        if (t < off) {
            float ov = rv[t + off]; int oi = ri[t + off];
            if (ov > rv[t] || (ov == rv[t] && oi < ri[t])) { rv[t] = ov; ri[t] = oi; }
        }
        __syncthreads();
    }
    if (t == 0) tok_out[0] = (float)ri[0];
}

// ==================== host launcher ====================
extern "C" void kernel_launch(void* const* d_in, const int* in_sizes, int n_in,
                              void* d_out, int out_size, void* d_ws, size_t ws_size,
                              hipStream_t stream) {
    P p;
    p.ids   = (const int*)d_in[0];
    p.aflag = (const int*)d_in[1];
    p.kc    = (const float*)d_in[2];
    p.vc    = (const float*)d_in[3];
    p.tbl   = (const int*)d_in[4];
    p.esc   = (const float*)d_in[5];
    p.ezp   = (const float*)d_in[6];
    p.w_in  = (const float*)d_in[7];
    p.w_qn  = (const float*)d_in[8];
    p.w_kn  = (const float*)d_in[9];
    p.Wq    = (const float*)d_in[10];
    p.Wk    = (const float*)d_in[11];
    p.Wv    = (const float*)d_in[12];
    p.Wo    = (const float*)d_in[13];
    p.w_pa  = (const float*)d_in[14];
    p.w_pf  = (const float*)d_in[15];
    p.w_pof = (const float*)d_in[16];
    p.Wg    = (const float*)d_in[17];
    p.Wu    = (const float*)d_in[18];
    p.Wd    = (const float*)d_in[19];
    p.w_fin = (const float*)d_in[20];
    p.Wlm   = (const float*)d_in[21];
    p.keys  = (float*)d_out;
    p.vals  = p.keys + (size_t)LNUM * DHEAD * SEQ;
    p.tok   = p.vals + (size_t)LNUM * SEQ * DHEAD;
    p.ws    = (float*)d_ws;
    float* ws = (float*)d_ws;

    void* args[] = { &p };
    hipError_t err = hipLaunchCooperativeKernel((void*)mega, dim3(NB), dim3(BS), args, 0, stream);

    if (err != hipSuccess) {
        // fallback: round-7 multi-kernel path (proven 579 µs)
        hipMemsetAsync(ws, 0, ZEND * sizeof(float), stream);
        gk_copy<<<24576 + 6144, 256, 0, stream>>>(p.kc, p.vc, p.keys, p.vals);
        for (int l = 0; l < LNUM; ++l) {
            float* QKVl = ws + QKV_O + (size_t)l * 1536;
            float* APl  = ws + AP_O + (size_t)l * DM;
            float* DPl  = ws + DP_O + (size_t)l * DM;
            float* GUl  = ws + GU_O + (size_t)l * 2 * FF;
            float* HINl = ws + HIN_O + (size_t)l * DM;
            float* HMl  = ws + HM_O + (size_t)l * DM;
            float* keys_l = p.keys + (size_t)l * DHEAD * SEQ;
            float* vals_l = p.vals + (size_t)l * SEQ * DHEAD;

            gk_qkv<<<dim3(6, 18), 256, 0, stream>>>(
                p.Wq + (size_t)l * DM * 1024, p.Wk + (size_t)l * DM * 256,
                p.Wv + (size_t)l * DM * 256, p.w_in + (size_t)l * DM,
                p.w_pof + (size_t)(l ? l - 1 : 0) * DM,
                (l ? ws + HM_O + (size_t)(l - 1) * DM : nullptr),
                (l ? ws + DP_O + (size_t)(l - 1) * DM : nullptr),
                p.ids, p.tbl, p.esc, p.ezp, HINl, QKVl, (l > 0) ? 1 : 0);

            gk_attn<<<128, 256, 0, stream>>>(
                QKVl, p.w_qn + (size_t)l * DHEAD, p.w_kn + (size_t)l * DHEAD,
                p.aflag, keys_l, vals_l, ws + POP_O, ws + SPS_O,
                ((l % 6) != 5) ? 1000000.0f : 10000.0f);

            gk_wo<<<dim3(5, 16), 256, 0, stream>>>(
                ws + POP_O, ws + SPS_O, p.Wo + (size_t)l * 1024 * DM, APl);

            gk_gu<<<dim3(54, 18), 256, 0, stream>>>(
                p.Wg + (size_t)l * DM * FF, p.Wu + (size_t)l * DM * FF,
                p.w_pa + (size_t)l * DM, p.w_pf + (size_t)l * DM, HINl, APl, HMl, GUl);

            gk_wd<<<dim3(5, 108), 256, 0, stream>>>(GUl, p.Wd + (size_t)l * FF * DM, DPl);
        }
        gk_logits<<<dim3(256, 18), 256, 0, stream>>>(
            p.Wlm, p.w_pof + (size_t)5 * DM, p.w_fin,
            ws + HM_O + (size_t)5 * DM, ws + DP_O + (size_t)5 * DM, ws + LG_O);
        gk_amax1<<<256, 256, 0, stream>>>(ws + LG_O, ws + AMV_O, ws + AMI_O);
        gk_amax2<<<1, 256, 0, stream>>>(ws + AMV_O, ws + AMI_O, p.tok);
    }
}

// Round 10
// 788.495 us; speedup vs baseline: 1.9660x; 1.9660x over previous
//
#include <hip/hip_runtime.h>
#include <hip/hip_fp16.h>
#include <cmath>

#define LNUM 6
#define DM   1152
#define DHEAD 256
#define NH   4
#define FF   6912
#define VOC  65536
#define HIST 4095
#define SEQ  4096
#define EPSV 1e-6f

// ---- ws float offsets (every region fully overwritten each call; no memset) ----
#define POP_O   0          // [128][1024]
#define SPS_O   131072     // [128][4]
#define QKVP_O  131584     // [18][1536]
#define APP_O   159232     // [16][1152]
#define DPP_O   177664     // [108][1152]
#define GUP_O   302080     // [18][13824]
#define LGP_O   550912     // [6][65536]
#define HIN_O   944128     // [6][1152]
#define HM_O    951040     // [6][1152]
#define XL_O    957952     // [1152]
#define AMX_O   959104     // u64 (8B-aligned: 959104*4 % 8 == 0)
#define CNT_O   959106     // u32

__device__ __forceinline__ float block_sum256(float v, float* red4) {
#pragma unroll
    for (int off = 32; off; off >>= 1) v += __shfl_xor(v, off);
    int t = threadIdx.x;
    if ((t & 63) == 0) red4[t >> 6] = v;
    __syncthreads();
    float r = red4[0] + red4[1] + red4[2] + red4[3];
    __syncthreads();
    return r;
}

// ---------------- cache copies (proven) ----------------
__global__ __launch_bounds__(256) void gk_copy(const float* __restrict__ kc,
                                               const float* __restrict__ vc,
                                               float* __restrict__ keys,
                                               float* __restrict__ vals) {
    int b = blockIdx.x;
    if (b < 24576) {
        int row = b >> 4;
        int s = ((b & 15) << 8) + threadIdx.x;
        if (s < HIST) keys[(size_t)row * SEQ + s] = kc[(size_t)row * HIST + s];
    } else {
        int r = (b - 24576) * 4 + (threadIdx.x >> 6);
        int d4 = threadIdx.x & 63;
        if (r < LNUM * HIST) {
            int l = r / HIST, sI = r - l * HIST;
            ((float4*)(vals + ((size_t)l * SEQ + sI) * DHEAD))[d4] =
                ((const float4*)(vc + (size_t)r * DHEAD))[d4];
        }
    }
}

// ---------------- qkv: deterministic inline prefix + GEMV -> QKVP partials ----------------
__global__ __launch_bounds__(256) void gk_qkv(
    const float* __restrict__ Wq, const float* __restrict__ Wk, const float* __restrict__ Wv,
    const float* __restrict__ wln, const float* __restrict__ wres,
    const float* __restrict__ hbase, const float* __restrict__ dpp,
    const int* __restrict__ ids, const int* __restrict__ tbl,
    const float* __restrict__ esc, const float* __restrict__ ezp,
    float* __restrict__ hin_out, float* __restrict__ qkvp, int has_prev) {
    __shared__ float xv[DM];
    __shared__ float red4[4];
    __shared__ float4 qred[256];
    int t = threadIdx.x;
    if (has_prev) {
        for (int i = t; i < DM; i += 256) {
            float d = 0.f;
#pragma unroll 4
            for (int p2 = 0; p2 < 108; ++p2) d += dpp[p2 * DM + i];
            xv[i] = d;
        }
        float ss = 0.f;
        for (int i = t; i < DM; i += 256) { float d = xv[i]; ss += d * d; }
        ss = block_sum256(ss, red4);
        float inv = 1.f / sqrtf(ss / DM + EPSV);
        for (int i = t; i < DM; i += 256)
            xv[i] = hbase[i] + wres[i] * xv[i] * inv;
    } else {
        int tok = ids[0];
        float sc = esc[tok], z = ezp[tok];
        const int* row = tbl + (size_t)tok * DM;
        for (int i = t; i < DM; i += 256) xv[i] = (float)row[i] * sc + z;
    }
    if (blockIdx.x == 0 && blockIdx.y == 0)
        for (int i = t; i < DM; i += 256) hin_out[i] = xv[i];
    float s2 = 0.f;
    for (int i = t; i < DM; i += 256) { float v = xv[i]; s2 += v * v; }
    s2 = block_sum256(s2, red4);
    float inv2 = 1.f / sqrtf(s2 / DM + EPSV);
    for (int i = t; i < DM; i += 256) xv[i] = wln[i] * xv[i] * inv2;
    __syncthreads();

    int f4c = t & 63, ks = t >> 6;
    int jf = blockIdx.x * 64 + f4c;          // 0..383
    const float4* W4; int jj4, ncol4;
    if (jf < 256)      { W4 = (const float4*)Wq; jj4 = jf;       ncol4 = 256; }
    else if (jf < 320) { W4 = (const float4*)Wk; jj4 = jf - 256; ncol4 = 64; }
    else               { W4 = (const float4*)Wv; jj4 = jf - 320; ncol4 = 64; }
    int i0 = blockIdx.y * 64 + ks * 16;
    float4 w[16];
#pragma unroll
    for (int r = 0; r < 16; ++r) w[r] = W4[(size_t)(i0 + r) * ncol4 + jj4];
    float4 acc = {0, 0, 0, 0};
#pragma unroll
    for (int r = 0; r < 16; ++r) {
        float xs = xv[i0 + r];
        acc.x += xs * w[r].x; acc.y += xs * w[r].y;
        acc.z += xs * w[r].z; acc.w += xs * w[r].w;
    }
    qred[t] = acc;
    __syncthreads();
    if (ks == 0) {
        float4 a = qred[f4c], b = qred[64 + f4c], c = qred[128 + f4c], d = qred[192 + f4c];
        float* dst = qkvp + (size_t)blockIdx.y * 1536 + 4 * jf;
        dst[0] = a.x + b.x + c.x + d.x;
        dst[1] = a.y + b.y + c.y + d.y;
        dst[2] = a.z + b.z + c.z + d.z;
        dst[3] = a.w + b.w + c.w + d.w;
    }
}

// ---------------- fused attention (reduces QKVP deterministically) ----------------
__global__ __launch_bounds__(256) void gk_attn(
    const float* __restrict__ qkvp, const float* __restrict__ w_qn,
    const float* __restrict__ w_kn, const int* __restrict__ attn_flag,
    float* __restrict__ keys_l, float* __restrict__ vals_l,
    float* __restrict__ po_part, float* __restrict__ sum_part, float rope_base) {
    __shared__ float lq[NH * DHEAD];
    __shared__ float lqf[NH * DHEAD];
    __shared__ float lkn[DHEAD];
    __shared__ float lkf[DHEAD];
    __shared__ float lv[DHEAD];
    __shared__ float lp[NH * 32];
    int t = threadIdx.x;
    int s0 = blockIdx.x * 32;
    bool last = (blockIdx.x == gridDim.x - 1);

    int jm = t & 127;
    float theta = powf(rope_base, -(float)(2 * jm) / 256.f);
    float ang = 4095.f * theta;
    float c = __half2float(__float2half(cosf(ang)));
    float s = __half2float(__float2half(sinf(ang)));

    // deterministic reduce of QKVP[18][1536]
    for (int j = t; j < 1536; j += 256) {
        float v = 0.f;
#pragma unroll
        for (int p2 = 0; p2 < 18; ++p2) v += qkvp[p2 * 1536 + j];
        if (j < 1024) lq[j] = v;
        else if (j < 1280) lkn[j - 1024] = v;
        else lv[j - 1280] = v;
    }
    __syncthreads();
    // wave-parallel head norms
    int wv = t >> 6, ln = t & 63;
    float sq = 0.f, sk = 0.f;
#pragma unroll
    for (int j = 0; j < 4; ++j) {
        float v = lq[wv * 256 + j * 64 + ln]; sq += v * v;
        float u = lkn[j * 64 + ln];           sk += u * u;
    }
#pragma unroll
    for (int off = 32; off; off >>= 1) { sq += __shfl_xor(sq, off); sk += __shfl_xor(sk, off); }
    float invq = 1.f / sqrtf(sq / 256.f + EPSV);
    float invk = 1.f / sqrtf(sk / 256.f + EPSV);
    __syncthreads();
#pragma unroll
    for (int j = 0; j < 4; ++j) {
        int d = j * 64 + ln;
        lq[wv * 256 + d] *= w_qn[d] * invq;
        if (wv == 0) lkn[d] *= w_kn[d] * invk;
    }
    __syncthreads();
    {
        float kn = lkn[t];
        float prk = (t < 128) ? -lkn[t + 128] : lkn[t - 128];
        lkf[t] = kn * c + prk * s;
#pragma unroll
        for (int h = 0; h < NH; ++h) {
            float qn = lq[h * 256 + t];
            float pr = (t < 128) ? -lq[h * 256 + t + 128] : lq[h * 256 + t - 128];
            lqf[h * 256 + t] = qn * c + pr * s;
        }
    }
    __syncthreads();
    if (last) {
        keys_l[(size_t)t * SEQ + (SEQ - 1)] = lkf[t];
        vals_l[(size_t)(SEQ - 1) * DHEAD + t] = lv[t];
    }
    int sl = t & 31, dc = t >> 5;
    int sg = s0 + sl;
    bool self = last && (sl == 31);
    float a0 = 0, a1 = 0, a2 = 0, a3 = 0;
#pragma unroll 4
    for (int dd = 0; dd < 32; ++dd) {
        int d = dc * 32 + dd;
        float kv = self ? lkf[d] : keys_l[(size_t)d * SEQ + sg];
        a0 += lqf[0 * 256 + d] * kv;
        a1 += lqf[1 * 256 + d] * kv;
        a2 += lqf[2 * 256 + d] * kv;
        a3 += lqf[3 * 256 + d] * kv;
    }
    __syncthreads();
    lq[0 * 256 + t] = a0; lq[1 * 256 + t] = a1; lq[2 * 256 + t] = a2; lq[3 * 256 + t] = a3;
    __syncthreads();
    if (t < 32) {
        int af = attn_flag[0];
        float mk = (s0 + t > 0) ? -128.f * (float)af : 0.f;
        for (int h = 0; h < NH; ++h) {
            float sc_ = 0.f;
#pragma unroll
            for (int d8 = 0; d8 < 8; ++d8) sc_ += lq[h * 256 + d8 * 32 + t];
            lp[h * 32 + t] = expf(sc_ + mk);
        }
    }
    __syncthreads();
    if (t < NH) {
        float su = 0.f;
        for (int i = 0; i < 32; ++i) su += lp[t * 32 + i];
        sum_part[blockIdx.x * NH + t] = su;
    }
    float p0 = 0, p1 = 0, p2 = 0, p3 = 0;
#pragma unroll 4
    for (int ss_ = 0; ss_ < 32; ++ss_) {
        float v = (last && ss_ == 31) ? lv[t] : vals_l[(size_t)(s0 + ss_) * DHEAD + t];
        p0 += lp[0 * 32 + ss_] * v;
        p1 += lp[1 * 32 + ss_] * v;
        p2 += lp[2 * 32 + ss_] * v;
        p3 += lp[3 * 32 + ss_] * v;
    }
    float* po = po_part + (size_t)blockIdx.x * NH * DHEAD;
    po[0 * 256 + t] = p0; po[1 * 256 + t] = p1; po[2 * 256 + t] = p2; po[3 * 256 + t] = p3;
}

// ---------------- wo -> APP partials, grid(5,16) ----------------
__global__ __launch_bounds__(256) void gk_wo(
    const float* __restrict__ po_part, const float* __restrict__ sum_part,
    const float* __restrict__ Wo_l, float* __restrict__ app) {
    __shared__ float x[64];
    __shared__ float hinv[NH];
    __shared__ float red4[4];
    int t = threadIdx.x;
    for (int h = 0; h < NH; ++h) {
        float v = (t < 128) ? sum_part[t * NH + h] : 0.f;
        float tot = block_sum256(v, red4);
        if (t == 0) hinv[h] = 1.f / tot;
    }
    __syncthreads();
    int i0 = blockIdx.y * 64;
    if (t < 64) {
        float a = 0.f;
#pragma unroll 8
        for (int b = 0; b < 128; ++b) a += po_part[(size_t)b * 1024 + i0 + t];
        x[t] = a * hinv[(i0 + t) >> 8];
    }
    __syncthreads();
    int j = blockIdx.x * 256 + t;
    if (j < DM) {
        float acc = 0.f;
#pragma unroll 4
        for (int ii = 0; ii < 64; ++ii)
            acc += x[ii] * Wo_l[(size_t)(i0 + ii) * DM + j];
        app[(size_t)blockIdx.y * DM + j] = acc;
    }
}

// ---------------- gu: deterministic inline prefix + GEMV -> GUP partials ----------------
__global__ __launch_bounds__(256) void gk_gu(
    const float* __restrict__ Wg_l, const float* __restrict__ Wu_l,
    const float* __restrict__ w_pa, const float* __restrict__ w_pf,
    const float* __restrict__ hin, const float* __restrict__ app,
    float* __restrict__ hm_out, float* __restrict__ gup) {
    __shared__ float xv[DM];
    __shared__ float red4[4];
    __shared__ float4 gred[256];
    int t = threadIdx.x;
    for (int i = t; i < DM; i += 256) {
        float a = 0.f;
#pragma unroll
        for (int p2 = 0; p2 < 16; ++p2) a += app[p2 * DM + i];
        xv[i] = a;
    }
    float ss = 0.f;
    for (int i = t; i < DM; i += 256) { float a = xv[i]; ss += a * a; }
    ss = block_sum256(ss, red4);
    float inv = 1.f / sqrtf(ss / DM + EPSV);
    for (int i = t; i < DM; i += 256) xv[i] = hin[i] + w_pa[i] * xv[i] * inv;
    if (blockIdx.x == 0 && blockIdx.y == 0)
        for (int i = t; i < DM; i += 256) hm_out[i] = xv[i];
    float s2 = 0.f;
    for (int i = t; i < DM; i += 256) { float v = xv[i]; s2 += v * v; }
    s2 = block_sum256(s2, red4);
    float inv2 = 1.f / sqrtf(s2 / DM + EPSV);
    for (int i = t; i < DM; i += 256) xv[i] = w_pf[i] * xv[i] * inv2;
    __syncthreads();

    int f4c = t & 63, ks = t >> 6;
    int cgi = blockIdx.x;
    bool isU = cgi >= 27;
    int cg = isU ? cgi - 27 : cgi;
    const float4* W4 = (const float4*)(isU ? Wu_l : Wg_l);
    int colf4 = cg * 64 + f4c;
    int i0 = blockIdx.y * 64 + ks * 16;
    float4 w[16];
#pragma unroll
    for (int r = 0; r < 16; ++r) w[r] = W4[(size_t)(i0 + r) * 1728 + colf4];
    float4 acc = {0, 0, 0, 0};
#pragma unroll
    for (int r = 0; r < 16; ++r) {
        float xs = xv[i0 + r];
        acc.x += xs * w[r].x; acc.y += xs * w[r].y;
        acc.z += xs * w[r].z; acc.w += xs * w[r].w;
    }
    gred[t] = acc;
    __syncthreads();
    if (ks == 0) {
        float4 a = gred[f4c], b = gred[64 + f4c], c = gred[128 + f4c], d = gred[192 + f4c];
        float* dst = gup + (size_t)blockIdx.y * 13824 + (isU ? FF : 0) + 4 * colf4;
        dst[0] = a.x + b.x + c.x + d.x;
        dst[1] = a.y + b.y + c.y + d.y;
        dst[2] = a.z + b.z + c.z + d.z;
        dst[3] = a.w + b.w + c.w + d.w;
    }
}

// ---------------- wd: reduce GUP + gelu + GEMV -> DPP partials, grid(5,108) ----------------
__global__ __launch_bounds__(256) void gk_wd(const float* __restrict__ gup,
                                             const float* __restrict__ Wd_l,
                                             float* __restrict__ dpp) {
    __shared__ float m[64];
    __shared__ float4 wred[256];
    int t = threadIdx.x;
    int i0 = blockIdx.y * 64;
    if (t < 64) {
        float g = 0.f, u = 0.f;
#pragma unroll
        for (int p2 = 0; p2 < 18; ++p2) {
            g += gup[(size_t)p2 * 13824 + i0 + t];
            u += gup[(size_t)p2 * 13824 + FF + i0 + t];
        }
        float gl = 0.5f * g * (1.f + tanhf(0.7978845608028654f * (g + 0.044715f * g * g * g)));
        m[t] = gl * u;
    }
    __syncthreads();
    int f4c = t & 63, ks = t >> 6;
    int col4 = blockIdx.x * 64 + f4c;        // valid < 288
    float4 acc = {0, 0, 0, 0};
    if (col4 < 288) {
        const float4* W4 = (const float4*)Wd_l;
        float4 w[16];
#pragma unroll
        for (int r = 0; r < 16; ++r) w[r] = W4[(size_t)(i0 + ks * 16 + r) * 288 + col4];
#pragma unroll
        for (int r = 0; r < 16; ++r) {
            float xs = m[ks * 16 + r];
            acc.x += xs * w[r].x; acc.y += xs * w[r].y;
            acc.z += xs * w[r].z; acc.w += xs * w[r].w;
        }
    }
    wred[t] = acc;
    __syncthreads();
    if (ks == 0 && col4 < 288) {
        float4 a = wred[f4c], b = wred[64 + f4c], c = wred[128 + f4c], d = wred[192 + f4c];
        float* dst = dpp + (size_t)blockIdx.y * DM + 4 * col4;
        dst[0] = a.x + b.x + c.x + d.x;
        dst[1] = a.y + b.y + c.y + d.y;
        dst[2] = a.z + b.z + c.z + d.z;
        dst[3] = a.w + b.w + c.w + d.w;
    }
}

// ---------------- prepL: final residual + RMS -> XL; zero argmax cells ----------------
__global__ __launch_bounds__(256) void gk_prepL(
    const float* __restrict__ hm5, const float* __restrict__ dpp,
    const float* __restrict__ wpof5, const float* __restrict__ wfin,
    float* __restrict__ xl, unsigned long long* __restrict__ amx,
    unsigned int* __restrict__ cnt) {
    __shared__ float xv[DM];
    __shared__ float red4[4];
    int t = threadIdx.x;
    for (int i = t; i < DM; i += 256) {
        float d = 0.f;
#pragma unroll 4
        for (int p2 = 0; p2 < 108; ++p2) d += dpp[p2 * DM + i];
        xv[i] = d;
    }
    float ss = 0.f;
    for (int i = t; i < DM; i += 256) { float d = xv[i]; ss += d * d; }
    ss = block_sum256(ss, red4);
    float inv = 1.f / sqrtf(ss / DM + EPSV);
    for (int i = t; i < DM; i += 256) xv[i] = hm5[i] + wpof5[i] * xv[i] * inv;
    float s2 = 0.f;
    for (int i = t; i < DM; i += 256) { float v = xv[i]; s2 += v * v; }
    s2 = block_sum256(s2, red4);
    float inv2 = 1.f / sqrtf(s2 / DM + EPSV);
    for (int i = t; i < DM; i += 256) xl[i] = wfin[i] * xv[i] * inv2;
    if (t == 0) { *amx = 0ull; *cnt = 0u; }
}

// ---------------- logits GEMV -> LGP partials, grid(256,6) ----------------
__global__ __launch_bounds__(256) void gk_logits(
    const float* __restrict__ W_lm, const float* __restrict__ xl,
    float* __restrict__ lgp) {
    __shared__ float4 lred[256];
    int t = threadIdx.x;
    int f4c = t & 63, ks = t >> 6;
    int colf4 = blockIdx.x * 64 + f4c;       // 0..16383
    const float4* W4 = (const float4*)W_lm;
    float4 acc = {0, 0, 0, 0};
#pragma unroll
    for (int bb = 0; bb < 3; ++bb) {
        int i0 = blockIdx.y * 192 + ks * 48 + bb * 16;
        float4 w[16];
#pragma unroll
        for (int r = 0; r < 16; ++r) w[r] = W4[(size_t)(i0 + r) * 16384 + colf4];
#pragma unroll
        for (int r = 0; r < 16; ++r) {
            float xs = xl[i0 + r];
            acc.x += xs * w[r].x; acc.y += xs * w[r].y;
            acc.z += xs * w[r].z; acc.w += xs * w[r].w;
        }
    }
    lred[t] = acc;
    __syncthreads();
    if (ks == 0) {
        float4 a = lred[f4c], b = lred[64 + f4c], c = lred[128 + f4c], d = lred[192 + f4c];
        float* dst = lgp + (size_t)blockIdx.y * VOC + 4 * colf4;
        dst[0] = a.x + b.x + c.x + d.x;
        dst[1] = a.y + b.y + c.y + d.y;
        dst[2] = a.z + b.z + c.z + d.z;
        dst[3] = a.w + b.w + c.w + d.w;
    }
}

// ---------------- argmax: deterministic packed u64 atomicMax + completion counter ----------------
__global__ __launch_bounds__(256) void gk_amax(
    const float* __restrict__ lgp, unsigned long long* __restrict__ amx,
    unsigned int* __restrict__ cnt, float* __restrict__ tok_out) {
    __shared__ unsigned long long smu[256];
    int t = threadIdx.x;
    int c = blockIdx.x * 256 + t;
    float v = 0.f;
#pragma unroll
    for (int p2 = 0; p2 < 6; ++p2) v += lgp[(size_t)p2 * VOC + c];
    unsigned bits = __float_as_uint(v);
    unsigned key = (bits & 0x80000000u) ? ~bits : (bits | 0x80000000u);
    smu[t] = ((unsigned long long)key << 32) | (unsigned)(~c);
    __syncthreads();
    for (int off = 128; off; off >>= 1) {
        if (t < off) { if (smu[t + off] > smu[t]) smu[t] = smu[t + off]; }
        __syncthreads();
    }
    if (t == 0) {
        atomicMax(amx, smu[0]);
        __threadfence();
        unsigned tk = atomicAdd(cnt, 1u);
        if (tk == 255u) {
            unsigned long long fin = atomicMax(amx, 0ull);  // read via atomic (L2-coherent)
            unsigned cc = ~(unsigned)(fin & 0xFFFFFFFFull);
            tok_out[0] = (float)cc;
        }
    }
}

// ==================== host launcher ====================
extern "C" void kernel_launch(void* const* d_in, const int* in_sizes, int n_in,
                              void* d_out, int out_size, void* d_ws, size_t ws_size,
                              hipStream_t stream) {
    const int*   ids   = (const int*)d_in[0];
    const int*   aflag = (const int*)d_in[1];
    const float* kc    = (const float*)d_in[2];
    const float* vc    = (const float*)d_in[3];
    const int*   tbl   = (const int*)d_in[4];
    const float* esc   = (const float*)d_in[5];
    const float* ezp   = (const float*)d_in[6];
    const float* w_in  = (const float*)d_in[7];
    const float* w_qn  = (const float*)d_in[8];
    const float* w_kn  = (const float*)d_in[9];
    const float* Wq    = (const float*)d_in[10];
    const float* Wk    = (const float*)d_in[11];
    const float* Wv    = (const float*)d_in[12];
    const float* Wo    = (const float*)d_in[13];
    const float* w_pa  = (const float*)d_in[14];
    const float* w_pf  = (const float*)d_in[15];
    const float* w_pof = (const float*)d_in[16];
    const float* Wg    = (const float*)d_in[17];
    const float* Wu    = (const float*)d_in[18];
    const float* Wd    = (const float*)d_in[19];
    const float* w_fin = (const float*)d_in[20];
    const float* Wlm   = (const float*)d_in[21];

    float* keys = (float*)d_out;
    float* vals = keys + (size_t)LNUM * DHEAD * SEQ;
    float* tok  = vals + (size_t)LNUM * SEQ * DHEAD;
    float* ws = (float*)d_ws;

    gk_copy<<<24576 + 6144, 256, 0, stream>>>(kc, vc, keys, vals);

    for (int l = 0; l < LNUM; ++l) {
        float* keys_l = keys + (size_t)l * DHEAD * SEQ;
        float* vals_l = vals + (size_t)l * SEQ * DHEAD;

        gk_qkv<<<dim3(6, 18), 256, 0, stream>>>(
            Wq + (size_t)l * DM * 1024, Wk + (size_t)l * DM * 256,
            Wv + (size_t)l * DM * 256,
            w_in + (size_t)l * DM,
            (l ? w_pof + (size_t)(l - 1) * DM : w_in),
            (l ? ws + HM_O + (size_t)(l - 1) * DM : nullptr),
            ws + DPP_O,
            ids, tbl, esc, ezp,
            ws + HIN_O + (size_t)l * DM, ws + QKVP_O, (l > 0) ? 1 : 0);

        gk_attn<<<128, 256, 0, stream>>>(
            ws + QKVP_O, w_qn + (size_t)l * DHEAD, w_kn + (size_t)l * DHEAD,
            aflag, keys_l, vals_l, ws + POP_O, ws + SPS_O,
            ((l % 6) != 5) ? 1000000.0f : 10000.0f);

        gk_wo<<<dim3(5, 16), 256, 0, stream>>>(
            ws + POP_O, ws + SPS_O, Wo + (size_t)l * 1024 * DM, ws + APP_O);

        gk_gu<<<dim3(54, 18), 256, 0, stream>>>(
            Wg + (size_t)l * DM * FF, Wu + (size_t)l * DM * FF,
            w_pa + (size_t)l * DM, w_pf + (size_t)l * DM,
            ws + HIN_O + (size_t)l * DM, ws + APP_O,
            ws + HM_O + (size_t)l * DM, ws + GUP_O);

        gk_wd<<<dim3(5, 108), 256, 0, stream>>>(
            ws + GUP_O, Wd + (size_t)l * FF * DM, ws + DPP_O);
    }

    gk_prepL<<<1, 256, 0, stream>>>(
        ws + HM_O + (size_t)5 * DM, ws + DPP_O,
        w_pof + (size_t)5 * DM, w_fin, ws + XL_O,
        (unsigned long long*)(ws + AMX_O), (unsigned int*)(ws + CNT_O));

    gk_logits<<<dim3(256, 6), 256, 0, stream>>>(Wlm, ws + XL_O, ws + LGP_O);

    gk_amax<<<256, 256, 0, stream>>>(
        ws + LGP_O, (unsigned long long*)(ws + AMX_O),
        (unsigned int*)(ws + CNT_O), tok);
}

// Round 13
// 555.428 us; speedup vs baseline: 2.7909x; 1.4196x over previous
//
#include <hip/hip_runtime.h>
#include <hip/hip_fp16.h>
#include <cmath>

#define LNUM 6
#define DM   1152
#define DHEAD 256
#define NH   4
#define FF   6912
#define VOC  65536
#define HIST 4095
#define SEQ  4096
#define EPSV 1e-6f

// ---- ws float offsets (all regions fully overwritten before read, every call) ----
#define POP_O   0          // [128][1024]
#define SPS_O   131072     // [128][4]
#define QKVP_O  131584     // [18][1536]
#define APP_O   159232     // [16][1152]
#define DPP_O   177664     // [27][1152]
#define GUP_O   208768     // [18][13824]
#define HIN_O   457600     // [1152]
#define HM_O    458752     // [1152]
#define XN0_O   459904     // [1152]
#define AMX_O   461056     // u64 (8B aligned)
#define CNT_O   461058     // [16] u32

__device__ __forceinline__ float block_sum256(float v, float* red4) {
#pragma unroll
    for (int off = 32; off; off >>= 1) v += __shfl_xor(v, off);
    int t = threadIdx.x;
    if ((t & 63) == 0) red4[t >> 6] = v;
    __syncthreads();
    float r = red4[0] + red4[1] + red4[2] + red4[3];
    __syncthreads();
    return r;
}

// ---------------- cache copies + embed + first RMS + counter init ----------------
__global__ __launch_bounds__(256) void gk_copy(
    const float* __restrict__ kc, const float* __restrict__ vc,
    float* __restrict__ keys, float* __restrict__ vals,
    const int* __restrict__ ids, const int* __restrict__ tbl,
    const float* __restrict__ esc, const float* __restrict__ ezp,
    const float* __restrict__ w_in0, float* __restrict__ hin0,
    float* __restrict__ xn0, unsigned int* __restrict__ cnts,
    unsigned long long* __restrict__ amx) {
    int b = blockIdx.x;
    int t = threadIdx.x;
    if (b < 24576) {
        int row = b >> 4;
        int s = ((b & 15) << 8) + t;
        if (s < HIST) keys[(size_t)row * SEQ + s] = kc[(size_t)row * HIST + s];
    } else {
        int r = (b - 24576) * 4 + (t >> 6);
        int d4 = t & 63;
        if (r < LNUM * HIST) {
            int l = r / HIST, sI = r - l * HIST;
            ((float4*)(vals + ((size_t)l * SEQ + sI) * DHEAD))[d4] =
                ((const float4*)(vc + (size_t)r * DHEAD))[d4];
        }
    }
    if (b == 0) {
        __shared__ float xv[DM];
        __shared__ float red4[4];
        int tok = ids[0];
        float sc = esc[tok], z = ezp[tok];
        const int* row = tbl + (size_t)tok * DM;
        for (int i = t; i < DM; i += 256) xv[i] = (float)row[i] * sc + z;
        for (int i = t; i < DM; i += 256) hin0[i] = xv[i];
        float ss = 0.f;
        for (int i = t; i < DM; i += 256) { float v = xv[i]; ss += v * v; }
        ss = block_sum256(ss, red4);
        float inv = 1.f / sqrtf(ss / DM + EPSV);
        for (int i = t; i < DM; i += 256) xn0[i] = w_in0[i] * xv[i] * inv;
        if (t < 16) cnts[t] = 0u;
        if (t == 0) *amx = 0ull;
    }
}

// ---------------- qkv: redundant prefix (reduce DPP[27] + residual + 2xRMS) + GEMV ----------------
__global__ __launch_bounds__(256) void gk_qkv(
    const float* __restrict__ Wq, const float* __restrict__ Wk, const float* __restrict__ Wv,
    const float* __restrict__ wln, const float* __restrict__ wres,
    const float* __restrict__ hm_prev, const float* __restrict__ dpp,
    const float* __restrict__ xn0,
    float* __restrict__ hin_out, float* __restrict__ qkvp, int has_prev) {
    __shared__ float xv[DM];
    __shared__ float red4[4];
    __shared__ float4 qred[256];
    int t = threadIdx.x;
    if (has_prev) {
        for (int i = t; i < DM; i += 256) {
            float d = 0.f;
#pragma unroll
            for (int p2 = 0; p2 < 27; ++p2) d += dpp[p2 * DM + i];
            xv[i] = d;
        }
        float ss = 0.f;
        for (int i = t; i < DM; i += 256) { float d = xv[i]; ss += d * d; }
        ss = block_sum256(ss, red4);
        float inv = 1.f / sqrtf(ss / DM + EPSV);
        for (int i = t; i < DM; i += 256) xv[i] = hm_prev[i] + wres[i] * xv[i] * inv;
        if (blockIdx.x == 0 && blockIdx.y == 0)
            for (int i = t; i < DM; i += 256) hin_out[i] = xv[i];
        float s2 = 0.f;
        for (int i = t; i < DM; i += 256) { float v = xv[i]; s2 += v * v; }
        s2 = block_sum256(s2, red4);
        float inv2 = 1.f / sqrtf(s2 / DM + EPSV);
        for (int i = t; i < DM; i += 256) xv[i] = wln[i] * xv[i] * inv2;
    } else {
        for (int i = t; i < DM; i += 256) xv[i] = xn0[i];
    }
    __syncthreads();

    int f4c = t & 63, ks = t >> 6;
    int jf = blockIdx.x * 64 + f4c;          // 0..383
    const float4* W4; int jj4, ncol4;
    if (jf < 256)      { W4 = (const float4*)Wq; jj4 = jf;       ncol4 = 256; }
    else if (jf < 320) { W4 = (const float4*)Wk; jj4 = jf - 256; ncol4 = 64; }
    else               { W4 = (const float4*)Wv; jj4 = jf - 320; ncol4 = 64; }
    int i0 = blockIdx.y * 64 + ks * 16;
    float4 w[16];
#pragma unroll
    for (int r = 0; r < 16; ++r) w[r] = W4[(size_t)(i0 + r) * ncol4 + jj4];
    float4 acc = {0, 0, 0, 0};
#pragma unroll
    for (int r = 0; r < 16; ++r) {
        float xs = xv[i0 + r];
        acc.x += xs * w[r].x; acc.y += xs * w[r].y;
        acc.z += xs * w[r].z; acc.w += xs * w[r].w;
    }
    qred[t] = acc;
    __syncthreads();
    if (ks == 0) {
        float4 a = qred[f4c], b = qred[64 + f4c], c = qred[128 + f4c], d = qred[192 + f4c];
        float* dst = qkvp + (size_t)blockIdx.y * 1536 + 4 * jf;
        dst[0] = a.x + b.x + c.x + d.x;
        dst[1] = a.y + b.y + c.y + d.y;
        dst[2] = a.z + b.z + c.z + d.z;
        dst[3] = a.w + b.w + c.w + d.w;
    }
}

// ---------------- fused attention (inline QKVP reduce; r10 proven) ----------------
__global__ __launch_bounds__(256) void gk_attn(
    const float* __restrict__ qkvp, const float* __restrict__ w_qn,
    const float* __restrict__ w_kn, const int* __restrict__ attn_flag,
    float* __restrict__ keys_l, float* __restrict__ vals_l,
    float* __restrict__ po_part, float* __restrict__ sum_part, float rope_base) {
    __shared__ float lq[NH * DHEAD];
    __shared__ float lqf[NH * DHEAD];
    __shared__ float lkn[DHEAD];
    __shared__ float lkf[DHEAD];
    __shared__ float lv[DHEAD];
    __shared__ float lp[NH * 32];
    int t = threadIdx.x;
    int s0 = blockIdx.x * 32;
    bool last = (blockIdx.x == gridDim.x - 1);

    int jm = t & 127;
    float theta = powf(rope_base, -(float)(2 * jm) / 256.f);
    float ang = 4095.f * theta;
    float c = __half2float(__float2half(cosf(ang)));
    float s = __half2float(__float2half(sinf(ang)));

    for (int j = t; j < 1536; j += 256) {
        float v = 0.f;
#pragma unroll
        for (int p2 = 0; p2 < 18; ++p2) v += qkvp[p2 * 1536 + j];
        if (j < 1024) lq[j] = v;
        else if (j < 1280) lkn[j - 1024] = v;
        else lv[j - 1280] = v;
    }
    __syncthreads();
    int wv = t >> 6, ln = t & 63;
    float sq = 0.f, sk = 0.f;
#pragma unroll
    for (int j = 0; j < 4; ++j) {
        float v = lq[wv * 256 + j * 64 + ln]; sq += v * v;
        float u = lkn[j * 64 + ln];           sk += u * u;
    }
#pragma unroll
    for (int off = 32; off; off >>= 1) { sq += __shfl_xor(sq, off); sk += __shfl_xor(sk, off); }
    float invq = 1.f / sqrtf(sq / 256.f + EPSV);
    float invk = 1.f / sqrtf(sk / 256.f + EPSV);
    __syncthreads();
#pragma unroll
    for (int j = 0; j < 4; ++j) {
        int d = j * 64 + ln;
        lq[wv * 256 + d] *= w_qn[d] * invq;
        if (wv == 0) lkn[d] *= w_kn[d] * invk;
    }
    __syncthreads();
    {
        float kn = lkn[t];
        float prk = (t < 128) ? -lkn[t + 128] : lkn[t - 128];
        lkf[t] = kn * c + prk * s;
#pragma unroll
        for (int h = 0; h < NH; ++h) {
            float qn = lq[h * 256 + t];
            float pr = (t < 128) ? -lq[h * 256 + t + 128] : lq[h * 256 + t - 128];
            lqf[h * 256 + t] = qn * c + pr * s;
        }
    }
    __syncthreads();
    if (last) {
        keys_l[(size_t)t * SEQ + (SEQ - 1)] = lkf[t];
        vals_l[(size_t)(SEQ - 1) * DHEAD + t] = lv[t];
    }
    int sl = t & 31, dc = t >> 5;
    int sg = s0 + sl;
    bool self = last && (sl == 31);
    float a0 = 0, a1 = 0, a2 = 0, a3 = 0;
#pragma unroll 4
    for (int dd = 0; dd < 32; ++dd) {
        int d = dc * 32 + dd;
        float kv = self ? lkf[d] : keys_l[(size_t)d * SEQ + sg];
        a0 += lqf[0 * 256 + d] * kv;
        a1 += lqf[1 * 256 + d] * kv;
        a2 += lqf[2 * 256 + d] * kv;
        a3 += lqf[3 * 256 + d] * kv;
    }
    __syncthreads();
    lq[0 * 256 + t] = a0; lq[1 * 256 + t] = a1; lq[2 * 256 + t] = a2; lq[3 * 256 + t] = a3;
    __syncthreads();
    if (t < 32) {
        int af = attn_flag[0];
        float mk = (s0 + t > 0) ? -128.f * (float)af : 0.f;
        for (int h = 0; h < NH; ++h) {
            float sc_ = 0.f;
#pragma unroll
            for (int d8 = 0; d8 < 8; ++d8) sc_ += lq[h * 256 + d8 * 32 + t];
            lp[h * 32 + t] = expf(sc_ + mk);
        }
    }
    __syncthreads();
    if (t < NH) {
        float su = 0.f;
        for (int i = 0; i < 32; ++i) su += lp[t * 32 + i];
        sum_part[blockIdx.x * NH + t] = su;
    }
    float p0 = 0, p1 = 0, p2 = 0, p3 = 0;
#pragma unroll 4
    for (int ss_ = 0; ss_ < 32; ++ss_) {
        float v = (last && ss_ == 31) ? lv[t] : vals_l[(size_t)(s0 + ss_) * DHEAD + t];
        p0 += lp[0 * 32 + ss_] * v;
        p1 += lp[1 * 32 + ss_] * v;
        p2 += lp[2 * 32 + ss_] * v;
        p3 += lp[3 * 32 + ss_] * v;
    }
    float* po = po_part + (size_t)blockIdx.x * NH * DHEAD;
    po[0 * 256 + t] = p0; po[1 * 256 + t] = p1; po[2 * 256 + t] = p2; po[3 * 256 + t] = p3;
}

// ---------------- wo -> APP partials, grid(5,16) (r10 proven) ----------------
__global__ __launch_bounds__(256) void gk_wo(
    const float* __restrict__ po_part, const float* __restrict__ sum_part,
    const float* __restrict__ Wo_l, float* __restrict__ app) {
    __shared__ float x[64];
    __shared__ float hinv[NH];
    __shared__ float red4[4];
    int t = threadIdx.x;
    for (int h = 0; h < NH; ++h) {
        float v = (t < 128) ? sum_part[t * NH + h] : 0.f;
        float tot = block_sum256(v, red4);
        if (t == 0) hinv[h] = 1.f / tot;
    }
    __syncthreads();
    int i0 = blockIdx.y * 64;
    if (t < 64) {
        float a = 0.f;
#pragma unroll 8
        for (int b = 0; b < 128; ++b) a += po_part[(size_t)b * 1024 + i0 + t];
        x[t] = a * hinv[(i0 + t) >> 8];
    }
    __syncthreads();
    int j = blockIdx.x * 256 + t;
    if (j < DM) {
        float acc = 0.f;
#pragma unroll 4
        for (int ii = 0; ii < 64; ++ii)
            acc += x[ii] * Wo_l[(size_t)(i0 + ii) * DM + j];
        app[(size_t)blockIdx.y * DM + j] = acc;
    }
}

// ---------------- gu: redundant prefix (reduce APP[16] + residual + 2xRMS) + GEMV ----------------
__global__ __launch_bounds__(256) void gk_gu(
    const float* __restrict__ Wg_l, const float* __restrict__ Wu_l,
    const float* __restrict__ w_pa, const float* __restrict__ w_pf,
    const float* __restrict__ hin, const float* __restrict__ app,
    float* __restrict__ hm_out, float* __restrict__ gup) {
    __shared__ float xv[DM];
    __shared__ float red4[4];
    __shared__ float4 gred[256];
    int t = threadIdx.x;
    for (int i = t; i < DM; i += 256) {
        float a = 0.f;
#pragma unroll
        for (int p2 = 0; p2 < 16; ++p2) a += app[p2 * DM + i];
        xv[i] = a;
    }
    float ss = 0.f;
    for (int i = t; i < DM; i += 256) { float a = xv[i]; ss += a * a; }
    ss = block_sum256(ss, red4);
    float inv = 1.f / sqrtf(ss / DM + EPSV);
    for (int i = t; i < DM; i += 256) xv[i] = hin[i] + w_pa[i] * xv[i] * inv;
    if (blockIdx.x == 0 && blockIdx.y == 0)
        for (int i = t; i < DM; i += 256) hm_out[i] = xv[i];
    float s2 = 0.f;
    for (int i = t; i < DM; i += 256) { float v = xv[i]; s2 += v * v; }
    s2 = block_sum256(s2, red4);
    float inv2 = 1.f / sqrtf(s2 / DM + EPSV);
    for (int i = t; i < DM; i += 256) xv[i] = w_pf[i] * xv[i] * inv2;
    __syncthreads();

    int f4c = t & 63, ks = t >> 6;
    int cgi = blockIdx.x;
    bool isU = cgi >= 27;
    int cg = isU ? cgi - 27 : cgi;
    const float4* W4 = (const float4*)(isU ? Wu_l : Wg_l);
    int colf4 = cg * 64 + f4c;
    int i0 = blockIdx.y * 64 + ks * 16;
    float4 w[16];
#pragma unroll
    for (int r = 0; r < 16; ++r) w[r] = W4[(size_t)(i0 + r) * 1728 + colf4];
    float4 acc = {0, 0, 0, 0};
#pragma unroll
    for (int r = 0; r < 16; ++r) {
        float xs = xv[i0 + r];
        acc.x += xs * w[r].x; acc.y += xs * w[r].y;
        acc.z += xs * w[r].z; acc.w += xs * w[r].w;
    }
    gred[t] = acc;
    __syncthreads();
    if (ks == 0) {
        float4 a = gred[f4c], b = gred[64 + f4c], c = gred[128 + f4c], d = gred[192 + f4c];
        float* dst = gup + (size_t)blockIdx.y * 13824 + (isU ? FF : 0) + 4 * colf4;
        dst[0] = a.x + b.x + c.x + d.x;
        dst[1] = a.y + b.y + c.y + d.y;
        dst[2] = a.z + b.z + c.z + d.z;
        dst[3] = a.w + b.w + c.w + d.w;
    }
}

// ---------------- wd: reduce GUP + gelu + GEMV -> DPP[27] partials, grid(9,27) ----------------
__global__ __launch_bounds__(256) void gk_wd(const float* __restrict__ gup,
                                             const float* __restrict__ Wd_l,
                                             float* __restrict__ dpp) {
    __shared__ float m[256];
    __shared__ float4 wred[256];
    int t = threadIdx.x;
    int i0 = blockIdx.y * 256;
    {
        float g = 0.f, u = 0.f;
#pragma unroll
        for (int p2 = 0; p2 < 18; ++p2) {
            g += gup[(size_t)p2 * 13824 + i0 + t];
            u += gup[(size_t)p2 * 13824 + FF + i0 + t];
        }
        float gl = 0.5f * g * (1.f + tanhf(0.7978845608028654f * (g + 0.044715f * g * g * g)));
        m[t] = gl * u;
    }
    __syncthreads();
    int f4c = t & 31, ks = t >> 5;           // 32 f4-cols x 8 k-slices (32 rows each)
    int col4 = blockIdx.x * 32 + f4c;        // 0..287
    const float4* W4 = (const float4*)Wd_l;
    float4 acc = {0, 0, 0, 0};
#pragma unroll
    for (int bb = 0; bb < 2; ++bb) {
        int rb = ks * 32 + bb * 16;
        float4 w[16];
#pragma unroll
        for (int r = 0; r < 16; ++r) w[r] = W4[(size_t)(i0 + rb + r) * 288 + col4];
#pragma unroll
        for (int r = 0; r < 16; ++r) {
            float xs = m[rb + r];
            acc.x += xs * w[r].x; acc.y += xs * w[r].y;
            acc.z += xs * w[r].z; acc.w += xs * w[r].w;
        }
    }
    wred[t] = acc;
    __syncthreads();
    if (t < 32) {
        float sx = 0, sy = 0, sz = 0, sw = 0;
#pragma unroll
        for (int k2 = 0; k2 < 8; ++k2) {
            float4 r = wred[k2 * 32 + t];
            sx += r.x; sy += r.y; sz += r.z; sw += r.w;
        }
        float* dst = dpp + (size_t)blockIdx.y * DM + 4 * (blockIdx.x * 32 + t);
        dst[0] = sx; dst[1] = sy; dst[2] = sz; dst[3] = sw;
    }
}

// ---------------- logits: redundant prefix + full-K GEMV + fused argmax, grid(256) ----------------
__global__ __launch_bounds__(256) void gk_logits(
    const float* __restrict__ W_lm,
    const float* __restrict__ hm5, const float* __restrict__ dpp,
    const float* __restrict__ wpof5, const float* __restrict__ wfin,
    unsigned long long* __restrict__ amx, unsigned int* __restrict__ cnt,
    float* __restrict__ tok_out) {
    __shared__ float xv[DM];
    __shared__ float red4[4];
    __shared__ float4 lred[256];
    __shared__ unsigned long long smu[64];
    int t = threadIdx.x;
    // prefix: reduce DPP[27] + residual + double RMS (identical in every block)
    for (int i = t; i < DM; i += 256) {
        float d = 0.f;
#pragma unroll
        for (int p2 = 0; p2 < 27; ++p2) d += dpp[p2 * DM + i];
        xv[i] = d;
    }
    float ss = 0.f;
    for (int i = t; i < DM; i += 256) { float d = xv[i]; ss += d * d; }
    ss = block_sum256(ss, red4);
    float inv = 1.f / sqrtf(ss / DM + EPSV);
    for (int i = t; i < DM; i += 256) xv[i] = hm5[i] + wpof5[i] * xv[i] * inv;
    float s2 = 0.f;
    for (int i = t; i < DM; i += 256) { float v = xv[i]; s2 += v * v; }
    s2 = block_sum256(s2, red4);
    float inv2 = 1.f / sqrtf(s2 / DM + EPSV);
    for (int i = t; i < DM; i += 256) xv[i] = wfin[i] * xv[i] * inv2;
    __syncthreads();

    int f4c = t & 63, ks = t >> 6;           // 4 k-slices of 288 rows
    int colf4 = blockIdx.x * 64 + f4c;
    const float4* W4 = (const float4*)W_lm;
    float4 acc = {0, 0, 0, 0};
    for (int bb = 0; bb < 18; ++bb) {
        int i0 = ks * 288 + bb * 16;
        float4 w[16];
#pragma unroll
        for (int r = 0; r < 16; ++r) w[r] = W4[(size_t)(i0 + r) * 16384 + colf4];
#pragma unroll
        for (int r = 0; r < 16; ++r) {
            float xs = xv[i0 + r];
            acc.x += xs * w[r].x; acc.y += xs * w[r].y;
            acc.z += xs * w[r].z; acc.w += xs * w[r].w;
        }
    }
    lred[t] = acc;
    __syncthreads();
    if (ks == 0) {
        float4 a = lred[f4c], b = lred[64 + f4c], c = lred[128 + f4c], d = lred[192 + f4c];
        float lv[4] = { a.x + b.x + c.x + d.x, a.y + b.y + c.y + d.y,
                        a.z + b.z + c.z + d.z, a.w + b.w + c.w + d.w };
        int c0 = blockIdx.x * 256 + 4 * f4c;   // FIXED: 256 scalar cols per block (was *1024)
        unsigned long long best = 0;
#pragma unroll
        for (int q = 0; q < 4; ++q) {
            unsigned bits = __float_as_uint(lv[q]);
            unsigned key = (bits & 0x80000000u) ? ~bits : (bits | 0x80000000u);
            unsigned long long pk = ((unsigned long long)key << 32) | (unsigned)(~(c0 + q));
            if (pk > best) best = pk;
        }
        smu[f4c] = best;
    }
    __syncthreads();
    for (int off = 32; off; off >>= 1) {
        if (t < off) { if (smu[t + off] > smu[t]) smu[t] = smu[t + off]; }
        __syncthreads();
    }
    if (t == 0) {
        atomicMax(amx, smu[0]);
        __threadfence();
        if (atomicAdd(cnt, 1u) == 255u) {
            unsigned long long fin = atomicMax(amx, 0ull);   // read via atomic (coherent)
            tok_out[0] = (float)(~(unsigned)(fin & 0xFFFFFFFFull));
        }
    }
}

// ==================== host launcher ====================
extern "C" void kernel_launch(void* const* d_in, const int* in_sizes, int n_in,
                              void* d_out, int out_size, void* d_ws, size_t ws_size,
                              hipStream_t stream) {
    const int*   ids   = (const int*)d_in[0];
    const int*   aflag = (const int*)d_in[1];
    const float* kc    = (const float*)d_in[2];
    const float* vc    = (const float*)d_in[3];
    const int*   tbl   = (const int*)d_in[4];
    const float* esc   = (const float*)d_in[5];
    const float* ezp   = (const float*)d_in[6];
    const float* w_in  = (const float*)d_in[7];
    const float* w_qn  = (const float*)d_in[8];
    const float* w_kn  = (const float*)d_in[9];
    const float* Wq    = (const float*)d_in[10];
    const float* Wk    = (const float*)d_in[11];
    const float* Wv    = (const float*)d_in[12];
    const float* Wo    = (const float*)d_in[13];
    const float* w_pa  = (const float*)d_in[14];
    const float* w_pf  = (const float*)d_in[15];
    const float* w_pof = (const float*)d_in[16];
    const float* Wg    = (const float*)d_in[17];
    const float* Wu    = (const float*)d_in[18];
    const float* Wd    = (const float*)d_in[19];
    const float* w_fin = (const float*)d_in[20];
    const float* Wlm   = (const float*)d_in[21];

    float* keys = (float*)d_out;
    float* vals = keys + (size_t)LNUM * DHEAD * SEQ;
    float* tok  = vals + (size_t)LNUM * SEQ * DHEAD;
    float* ws = (float*)d_ws;
    unsigned int* cnts = (unsigned int*)(ws + CNT_O);
    unsigned long long* amx = (unsigned long long*)(ws + AMX_O);

    gk_copy<<<24576 + 6144, 256, 0, stream>>>(
        kc, vc, keys, vals, ids, tbl, esc, ezp,
        w_in, ws + HIN_O, ws + XN0_O, cnts, amx);

    for (int l = 0; l < LNUM; ++l) {
        float* keys_l = keys + (size_t)l * DHEAD * SEQ;
        float* vals_l = vals + (size_t)l * SEQ * DHEAD;

        gk_qkv<<<dim3(6, 18), 256, 0, stream>>>(
            Wq + (size_t)l * DM * 1024, Wk + (size_t)l * DM * 256,
            Wv + (size_t)l * DM * 256,
            w_in + (size_t)l * DM,
            (l ? w_pof + (size_t)(l - 1) * DM : w_in),
            ws + HM_O, ws + DPP_O, ws + XN0_O,
            ws + HIN_O, ws + QKVP_O, (l > 0) ? 1 : 0);

        gk_attn<<<128, 256, 0, stream>>>(
            ws + QKVP_O, w_qn + (size_t)l * DHEAD, w_kn + (size_t)l * DHEAD,
            aflag, keys_l, vals_l, ws + POP_O, ws + SPS_O,
            ((l % 6) != 5) ? 1000000.0f : 10000.0f);

        gk_wo<<<dim3(5, 16), 256, 0, stream>>>(
            ws + POP_O, ws + SPS_O, Wo + (size_t)l * 1024 * DM, ws + APP_O);

        gk_gu<<<dim3(54, 18), 256, 0, stream>>>(
            Wg + (size_t)l * DM * FF, Wu + (size_t)l * DM * FF,
            w_pa + (size_t)l * DM, w_pf + (size_t)l * DM,
            ws + HIN_O, ws + APP_O, ws + HM_O, ws + GUP_O);

        gk_wd<<<dim3(9, 27), 256, 0, stream>>>(
            ws + GUP_O, Wd + (size_t)l * FF * DM, ws + DPP_O);
    }

    gk_logits<<<256, 256, 0, stream>>>(
        Wlm, ws + HM_O, ws + DPP_O,
        w_pof + (size_t)5 * DM, w_fin, amx, &cnts[0], tok);
}